// Round 1
// baseline (348.110 us; speedup 1.0000x reference)
//
#include <hip/hip_runtime.h>
#include <hip/hip_bf16.h>

// FastBinaryLinear: y[t,o] = scale[o] * sum_i x[t,i]*sign(w[o,i])
// Strategy: pre-pass x->bf16, w->sign(w) in bf16 (+/-1 exact) into d_ws,
// then bf16 MFMA GEMM C = A * B^T (both operands K-contiguous), f32 epilogue
// with per-column scale. m97-structure: 128x128 tile, BK=32, 4 waves,
// global_load_lds width 16, 16x16x32 MFMA, 4x4 frags/wave.

#define BM 128
#define BN 128
#define BK 32

typedef __bf16 bf16x8 __attribute__((ext_vector_type(8)));
typedef float f32x4 __attribute__((ext_vector_type(4)));

typedef const __attribute__((address_space(1))) void* gptr_t;
typedef __attribute__((address_space(3))) void* lptr_t;

// ---- round-to-nearest-even f32 -> bf16 (inputs are finite normals) ----
__device__ __forceinline__ unsigned short f32_to_bf16_rne(float f) {
  unsigned int u = __builtin_bit_cast(unsigned int, f);
  u += 0x7fffu + ((u >> 16) & 1u);
  return (unsigned short)(u >> 16);
}

__global__ __launch_bounds__(256) void cvt_x_kernel(const float4* __restrict__ in,
                                                    ushort4* __restrict__ out, int n4) {
  int stride = gridDim.x * blockDim.x;
  for (int i = blockIdx.x * blockDim.x + threadIdx.x; i < n4; i += stride) {
    float4 f = in[i];
    ushort4 o;
    o.x = f32_to_bf16_rne(f.x);
    o.y = f32_to_bf16_rne(f.y);
    o.z = f32_to_bf16_rne(f.z);
    o.w = f32_to_bf16_rne(f.w);
    out[i] = o;
  }
}

__device__ __forceinline__ unsigned short sign_bf16(float f) {
  // +1.0 bf16 = 0x3F80, -1.0 = 0xBF80, 0 -> 0
  return f > 0.f ? (unsigned short)0x3F80u : (f < 0.f ? (unsigned short)0xBF80u : (unsigned short)0u);
}

__global__ __launch_bounds__(256) void binarize_w_kernel(const float4* __restrict__ in,
                                                         ushort4* __restrict__ out, int n4) {
  int stride = gridDim.x * blockDim.x;
  for (int i = blockIdx.x * blockDim.x + threadIdx.x; i < n4; i += stride) {
    float4 f = in[i];
    ushort4 o;
    o.x = sign_bf16(f.x);
    o.y = sign_bf16(f.y);
    o.z = sign_bf16(f.z);
    o.w = sign_bf16(f.w);
    out[i] = o;
  }
}

// ---- bf16 GEMM, C[M][N] = A[M][K] * B[N][K]^T, scale per column ----
__global__ __launch_bounds__(256) void gemm_bt_kernel(
    const __hip_bfloat16* __restrict__ A,   // [M][K] bf16 (x)
    const __hip_bfloat16* __restrict__ B,   // [N][K] bf16 (sign(w))
    const float* __restrict__ scale,        // [N]
    float* __restrict__ C,                  // [M][N] f32
    int M, int N, int K) {
  __shared__ __align__(16) __hip_bfloat16 As[BM * BK];  // 8 KiB
  __shared__ __align__(16) __hip_bfloat16 Bs[BN * BK];  // 8 KiB

  const int t = threadIdx.x;    // 0..255
  const int wv = t >> 6;        // wave 0..3
  const int lane = t & 63;

  const int nb = N / BN;
  const int bn = blockIdx.x % nb;
  const int bm = blockIdx.x / nb;
  const int m0 = bm * BM, n0 = bn * BN;

  // staging coords: thread t covers LDS bytes t*16 (per 4096B issue = 64 rows)
  const int sub = t & 3;        // which 8-bf16 chunk within a 32-elem row
  const int rin = t >> 2;       // row 0..63 within the issue half
  const size_t a_base = (size_t)(m0 + rin) * K + sub * 8;
  const size_t b_base = (size_t)(n0 + rin) * K + sub * 8;
  char* lasA = (char*)As + wv * 1024;  // wave-uniform LDS base (+lane*16 by HW)
  char* lasB = (char*)Bs + wv * 1024;

  // compute coords: wave 2x2 grid, each wave owns 64x64 output
  const int wm = (wv >> 1) * 64;
  const int wn = (wv & 1) * 64;
  const int lr = lane & 15;            // fragment row (A) / col (B)
  const int lk = (lane >> 4) * 8;      // k-base within BK=32

  f32x4 acc[4][4];
#pragma unroll
  for (int i = 0; i < 4; i++)
#pragma unroll
    for (int j = 0; j < 4; j++) acc[i][j] = (f32x4)(0.0f);

  for (int k0 = 0; k0 < K; k0 += BK) {
    if (k0) __syncthreads();  // previous tile fully consumed before overwrite
    // A tile: rows [m0, m0+128), 2 issues of 64 rows
    __builtin_amdgcn_global_load_lds((gptr_t)(A + a_base + k0),                   (lptr_t)(lasA),         16, 0, 0);
    __builtin_amdgcn_global_load_lds((gptr_t)(A + a_base + (size_t)64 * K + k0),  (lptr_t)(lasA + 4096),  16, 0, 0);
    // B tile: rows [n0, n0+128)
    __builtin_amdgcn_global_load_lds((gptr_t)(B + b_base + k0),                   (lptr_t)(lasB),         16, 0, 0);
    __builtin_amdgcn_global_load_lds((gptr_t)(B + b_base + (size_t)64 * K + k0),  (lptr_t)(lasB + 4096),  16, 0, 0);
    __syncthreads();  // drains vmcnt -> tiles visible

    bf16x8 af[4], bg[4];
#pragma unroll
    for (int fm = 0; fm < 4; fm++)
      af[fm] = *reinterpret_cast<const bf16x8*>(&As[(wm + fm * 16 + lr) * BK + lk]);
#pragma unroll
    for (int fn = 0; fn < 4; fn++)
      bg[fn] = *reinterpret_cast<const bf16x8*>(&Bs[(wn + fn * 16 + lr) * BK + lk]);
#pragma unroll
    for (int fm = 0; fm < 4; fm++)
#pragma unroll
      for (int fn = 0; fn < 4; fn++)
        acc[fm][fn] = __builtin_amdgcn_mfma_f32_16x16x32_bf16(af[fm], bg[fn], acc[fm][fn], 0, 0, 0);
  }

  // epilogue: C/D layout col=lane&15, row=(lane>>4)*4+reg
  const int cr = (lane >> 4) * 4;
  const int cc = lane & 15;
#pragma unroll
  for (int fn = 0; fn < 4; fn++) {
    const int col = n0 + wn + fn * 16 + cc;
    const float s = scale[col];
#pragma unroll
    for (int fm = 0; fm < 4; fm++) {
      const int row = m0 + wm + fm * 16 + cr;
#pragma unroll
      for (int j = 0; j < 4; j++) {
        C[(size_t)(row + j) * N + col] = acc[fm][fn][j] * s;
      }
    }
  }
}

// ---- fallback (ws too small / odd shapes): f32 tiled GEMM ----
__global__ __launch_bounds__(256) void fallback_gemm_kernel(
    const float* __restrict__ x, const float* __restrict__ w,
    const float* __restrict__ scale, float* __restrict__ out,
    int M, int N, int K) {
  __shared__ float xs[16][17];
  __shared__ float ws_[16][17];
  int nb = N / 16;
  int bx = blockIdx.x % nb;
  int by = blockIdx.x / nb;
  int tx = threadIdx.x % 16;
  int ty = threadIdx.x / 16;
  float acc = 0.f;
  for (int k0 = 0; k0 < K; k0 += 16) {
    xs[ty][tx] = x[(size_t)(by * 16 + ty) * K + k0 + tx];
    float wv = w[(size_t)(bx * 16 + ty) * K + k0 + tx];
    ws_[ty][tx] = (float)((wv > 0.f) - (wv < 0.f));
    __syncthreads();
#pragma unroll
    for (int kk = 0; kk < 16; kk++) acc += xs[ty][kk] * ws_[tx][kk];
    __syncthreads();
  }
  int row = by * 16 + ty, col = bx * 16 + tx;
  out[(size_t)row * N + col] = acc * scale[col];
}

extern "C" void kernel_launch(void* const* d_in, const int* in_sizes, int n_in,
                              void* d_out, int out_size, void* d_ws, size_t ws_size,
                              hipStream_t stream) {
  const float* x = (const float*)d_in[0];
  const float* w = (const float*)d_in[1];
  const float* scale = (const float*)d_in[2];
  float* out = (float*)d_out;

  const int N = in_sizes[2];             // OUT_FEATURES (scale count)
  const int K = in_sizes[1] / N;         // IN_FEATURES
  const int M = in_sizes[0] / K;         // TOKENS

  const size_t xb_bytes = (size_t)M * K * 2;
  const size_t wb_bytes = (size_t)N * K * 2;
  const bool shapes_ok = (M % BM == 0) && (N % BN == 0) && (K % BK == 0);

  if (shapes_ok && ws_size >= xb_bytes + wb_bytes) {
    __hip_bfloat16* xb = (__hip_bfloat16*)d_ws;
    __hip_bfloat16* wb = (__hip_bfloat16*)((char*)d_ws + xb_bytes);

    cvt_x_kernel<<<2048, 256, 0, stream>>>((const float4*)x, (ushort4*)xb, M * (K / 4));
    binarize_w_kernel<<<2048, 256, 0, stream>>>((const float4*)w, (ushort4*)wb, N * (K / 4));

    int grid = (M / BM) * (N / BN);
    gemm_bt_kernel<<<grid, 256, 0, stream>>>(xb, wb, scale, out, M, N, K);
  } else {
    int grid = (M / 16) * (N / 16);
    fallback_gemm_kernel<<<grid, 256, 0, stream>>>(x, w, scale, out, M, N, K);
  }
}

// Round 2
// 272.797 us; speedup vs baseline: 1.2761x; 1.2761x over previous
//
#include <hip/hip_runtime.h>
#include <hip/hip_bf16.h>

// FastBinaryLinear: y[t,o] = scale[o] * sum_i x[t,i]*sign(w[o,i])
// Pre-pass: x->bf16, w->sign(w) bf16 into d_ws. Main: 256x256 8-phase bf16
// MFMA GEMM (T2 swizzle + T3/T4 counted vmcnt + T5 setprio), f32 epilogue.

typedef __bf16 bf16x8 __attribute__((ext_vector_type(8)));
typedef float f32x4 __attribute__((ext_vector_type(4)));
typedef const __attribute__((address_space(1))) void* gptr_t;
typedef __attribute__((address_space(3))) void* lptr_t;

#define LDS_BUF 65536

template<bool V> struct BoolC { static constexpr bool value = V; };

// ---- f32 -> bf16 RNE ----
__device__ __forceinline__ unsigned short f32_to_bf16_rne(float f) {
  unsigned int u = __builtin_bit_cast(unsigned int, f);
  u += 0x7fffu + ((u >> 16) & 1u);
  return (unsigned short)(u >> 16);
}

__global__ __launch_bounds__(256) void cvt_x_kernel(const float4* __restrict__ in,
                                                    ushort4* __restrict__ out, int n4) {
  int stride = gridDim.x * blockDim.x;
  for (int i = blockIdx.x * blockDim.x + threadIdx.x; i < n4; i += stride) {
    float4 f = in[i];
    ushort4 o;
    o.x = f32_to_bf16_rne(f.x);
    o.y = f32_to_bf16_rne(f.y);
    o.z = f32_to_bf16_rne(f.z);
    o.w = f32_to_bf16_rne(f.w);
    out[i] = o;
  }
}

__device__ __forceinline__ unsigned short sign_bf16(float f) {
  return f > 0.f ? (unsigned short)0x3F80u : (f < 0.f ? (unsigned short)0xBF80u : (unsigned short)0u);
}

__global__ __launch_bounds__(256) void binarize_w_kernel(const float4* __restrict__ in,
                                                         ushort4* __restrict__ out, int n4) {
  int stride = gridDim.x * blockDim.x;
  for (int i = blockIdx.x * blockDim.x + threadIdx.x; i < n4; i += stride) {
    float4 f = in[i];
    ushort4 o;
    o.x = sign_bf16(f.x);
    o.y = sign_bf16(f.y);
    o.z = sign_bf16(f.z);
    o.w = sign_bf16(f.w);
    out[i] = o;
  }
}

template<int MF0>
__device__ __forceinline__ void mfma16(f32x4 (&acc)[8][4], const bf16x8 (&a0)[2][2],
                                       const bf16x8 (&b0)[4][2]) {
#pragma unroll
  for (int j = 0; j < 2; j++)
#pragma unroll
    for (int nf = 0; nf < 4; nf++)
#pragma unroll
      for (int kk = 0; kk < 2; kk++)
        acc[MF0 + j][nf] =
            __builtin_amdgcn_mfma_f32_16x16x32_bf16(a0[j][kk], b0[nf][kk], acc[MF0 + j][nf], 0, 0, 0);
}

// ---- 256x256 8-phase GEMM: C[M][N] = A[M][K] * B[N][K]^T, per-col scale ----
// LDS half-tile layout: 16 subtiles (16 rows x 32 cols bf16 = 1024B each),
// sub = (r>>4)*2 + (c>>5); within: (r&15)*64 + (g ^ ((r>>1)&3))*16 + (c&7)*2,
// g = (c&31)>>3.  Swizzle is both-sides: linear global_load_lds dest +
// inverse-swizzled per-lane global source; ds_read applies same XOR.
__global__ __launch_bounds__(512, 2) void gemm256_kernel(
    const __hip_bfloat16* __restrict__ A,   // [M][K] bf16
    const __hip_bfloat16* __restrict__ B,   // [N][K] bf16 (+-1)
    const float* __restrict__ scale,        // [N]
    float* __restrict__ C,                  // [M][N] f32
    int M, int N, int K) {
  __shared__ __align__(16) char lds[131072];

  const int t = threadIdx.x;
  const int lane = t & 63;
  const int wv = t >> 6;
  const int wm = wv >> 2;   // 0..1
  const int wn = wv & 3;    // 0..3

  const int nbn = N >> 8;
  const int bn = blockIdx.x % nbn;
  const int bm = blockIdx.x / nbn;
  const int m0 = bm << 8, n0 = bn << 8;

  // staging: thread t's (row, col) within an 8KB issue (64 rows x 64 cols),
  // carrying the inverse granule swizzle.
  const int rlo = ((t >> 7) << 4) | ((t >> 2) & 15);
  const int gsw = (t & 3) ^ ((t >> 3) & 3);
  const int c0e = (((t >> 6) & 1) << 5) | (gsw << 3);
  const __hip_bfloat16* gA = A + (size_t)(m0 + rlo) * K + c0e;
  const __hip_bfloat16* gB = B + (size_t)(n0 + rlo) * K + c0e;
  const int stBase = wv << 10;  // wave-uniform LDS base; HW adds lane*16

  // ds_read lane bases (swizzled granule)
  const int rho = lane & 15;
  const int gpr = (lane >> 4) ^ ((lane >> 1) & 3);
  const int dsA = (wm << 14) + (rho << 6) + (gpr << 4);
  const int dsB = 32768 + ((wn >> 1) << 14) + ((wn & 1) << 13) + (rho << 6) + (gpr << 4);

#define STAGE(MAT, HALF, G64, KT, BUF)                                                   \
  __builtin_amdgcn_global_load_lds(                                                      \
      (gptr_t)(((MAT) ? gB : gA) + (size_t)((HALF)*128 + (G64)*64) * K + (size_t)(KT)*64), \
      (lptr_t)(lds + (BUF)*LDS_BUF + (MAT)*32768 + (HALF)*16384 + (G64)*8192 + stBase),  \
      16, 0, 0)

#define RD_A(MF, KK, BUF) (*(const bf16x8*)(lds + (BUF)*LDS_BUF + dsA + ((MF)*2 + (KK))*1024))
#define RD_B(NF, KK, BUF) (*(const bf16x8*)(lds + (BUF)*LDS_BUF + dsB + ((NF)*2 + (KK))*1024))
#define BAR() asm volatile("s_barrier" ::: "memory")

  f32x4 acc[8][4];
#pragma unroll
  for (int i = 0; i < 8; i++)
#pragma unroll
    for (int j = 0; j < 4; j++) acc[i][j] = (f32x4)(0.0f);

  // ---- prologue: tile 0 fully (8 loads), tile 1 minus A-g0 (6 loads) ----
  STAGE(0, 0, 0, 0, 0); STAGE(0, 0, 1, 0, 0); STAGE(0, 1, 0, 0, 0); STAGE(0, 1, 1, 0, 0);
  STAGE(1, 0, 0, 0, 0); STAGE(1, 0, 1, 0, 0); STAGE(1, 1, 0, 0, 0); STAGE(1, 1, 1, 0, 0);
  STAGE(1, 0, 0, 1, 1); STAGE(1, 0, 1, 1, 1); STAGE(1, 1, 0, 1, 1); STAGE(1, 1, 1, 1, 1);
  STAGE(0, 0, 1, 1, 1); STAGE(0, 1, 1, 1, 1);
  asm volatile("s_waitcnt vmcnt(6)" ::: "memory");
  BAR();

  bf16x8 a0[2][2], b0[4][2];

  auto run_iter = [&](int i, auto fullc) {
    constexpr bool FULL = decltype(fullc)::value;
    const int kt1 = 2 * i + 1, kt2 = 2 * i + 2, kt3 = 2 * i + 3;

    // ===== phase 0: tile 2i (buf0), B-load + mfrags 6,7 =====
#pragma unroll
    for (int nf = 0; nf < 4; nf++) { b0[nf][0] = RD_B(nf, 0, 0); b0[nf][1] = RD_B(nf, 1, 0); }
    a0[0][0] = RD_A(6, 0, 0); a0[0][1] = RD_A(6, 1, 0);
    a0[1][0] = RD_A(7, 0, 0); a0[1][1] = RD_A(7, 1, 0);
    STAGE(0, 0, 0, kt1, 1); STAGE(0, 1, 0, kt1, 1);
    BAR();
    __builtin_amdgcn_s_setprio(1); mfma16<6>(acc, a0, b0); __builtin_amdgcn_s_setprio(0);
    BAR();

    // ===== phase 1: mfrags 4,5 =====
    a0[0][0] = RD_A(4, 0, 0); a0[0][1] = RD_A(4, 1, 0);
    a0[1][0] = RD_A(5, 0, 0); a0[1][1] = RD_A(5, 1, 0);
    if constexpr (FULL) { STAGE(1, 0, 0, kt2, 0); STAGE(1, 0, 1, kt2, 0); }
    BAR();
    __builtin_amdgcn_s_setprio(1); mfma16<4>(acc, a0, b0); __builtin_amdgcn_s_setprio(0);
    BAR();

    // ===== phase 2: mfrags 2,3 =====
    a0[0][0] = RD_A(2, 0, 0); a0[0][1] = RD_A(2, 1, 0);
    a0[1][0] = RD_A(3, 0, 0); a0[1][1] = RD_A(3, 1, 0);
    if constexpr (FULL) { STAGE(1, 1, 0, kt2, 0); STAGE(1, 1, 1, kt2, 0); }
    BAR();
    __builtin_amdgcn_s_setprio(1); mfma16<2>(acc, a0, b0); __builtin_amdgcn_s_setprio(0);
    BAR();

    // ===== phase 3: mfrags 0,1; vmcnt gate for buf1 reads =====
    a0[0][0] = RD_A(0, 0, 0); a0[0][1] = RD_A(0, 1, 0);
    a0[1][0] = RD_A(1, 0, 0); a0[1][1] = RD_A(1, 1, 0);
    if constexpr (FULL) { STAGE(0, 0, 1, kt2, 0); STAGE(0, 1, 1, kt2, 0); }
    BAR();
    __builtin_amdgcn_s_setprio(1); mfma16<0>(acc, a0, b0); __builtin_amdgcn_s_setprio(0);
    if constexpr (FULL) asm volatile("s_waitcnt vmcnt(6)" ::: "memory");
    else                asm volatile("s_waitcnt vmcnt(0)" ::: "memory");
    BAR();

    // ===== phase 4: tile 2i+1 (buf1), B-load + mfrags 6,7 =====
#pragma unroll
    for (int nf = 0; nf < 4; nf++) { b0[nf][0] = RD_B(nf, 0, 1); b0[nf][1] = RD_B(nf, 1, 1); }
    a0[0][0] = RD_A(6, 0, 1); a0[0][1] = RD_A(6, 1, 1);
    a0[1][0] = RD_A(7, 0, 1); a0[1][1] = RD_A(7, 1, 1);
    if constexpr (FULL) { STAGE(0, 0, 0, kt2, 0); STAGE(0, 1, 0, kt2, 0); }
    BAR();
    __builtin_amdgcn_s_setprio(1); mfma16<6>(acc, a0, b0); __builtin_amdgcn_s_setprio(0);
    BAR();

    // ===== phase 5: mfrags 4,5 =====
    a0[0][0] = RD_A(4, 0, 1); a0[0][1] = RD_A(4, 1, 1);
    a0[1][0] = RD_A(5, 0, 1); a0[1][1] = RD_A(5, 1, 1);
    if constexpr (FULL) { STAGE(1, 0, 0, kt3, 1); STAGE(1, 0, 1, kt3, 1); }
    BAR();
    __builtin_amdgcn_s_setprio(1); mfma16<4>(acc, a0, b0); __builtin_amdgcn_s_setprio(0);
    BAR();

    // ===== phase 6: mfrags 2,3 =====
    a0[0][0] = RD_A(2, 0, 1); a0[0][1] = RD_A(2, 1, 1);
    a0[1][0] = RD_A(3, 0, 1); a0[1][1] = RD_A(3, 1, 1);
    if constexpr (FULL) { STAGE(1, 1, 0, kt3, 1); STAGE(1, 1, 1, kt3, 1); }
    BAR();
    __builtin_amdgcn_s_setprio(1); mfma16<2>(acc, a0, b0); __builtin_amdgcn_s_setprio(0);
    BAR();

    // ===== phase 7: mfrags 0,1; vmcnt gate for next-iter buf0 reads =====
    a0[0][0] = RD_A(0, 0, 1); a0[0][1] = RD_A(0, 1, 1);
    a0[1][0] = RD_A(1, 0, 1); a0[1][1] = RD_A(1, 1, 1);
    if constexpr (FULL) { STAGE(0, 0, 1, kt3, 1); STAGE(0, 1, 1, kt3, 1); }
    BAR();
    __builtin_amdgcn_s_setprio(1); mfma16<0>(acc, a0, b0); __builtin_amdgcn_s_setprio(0);
    if constexpr (FULL) asm volatile("s_waitcnt vmcnt(6)" ::: "memory");
    else                asm volatile("s_waitcnt vmcnt(0)" ::: "memory");
    BAR();
  };

  const int half_nt = K >> 7;
  for (int i = 0; i < half_nt - 1; ++i) run_iter(i, BoolC<true>{});
  run_iter(half_nt - 1, BoolC<false>{});

  // ---- epilogue: C/D layout col=lane&15, row=(lane>>4)*4+j ----
  const int cc = lane & 15;
  const int cr4 = (lane >> 4) << 2;
#pragma unroll
  for (int nf = 0; nf < 4; nf++) {
    const int col = n0 + wn * 64 + nf * 16 + cc;
    const float s = scale[col];
#pragma unroll
    for (int mf = 0; mf < 8; mf++) {
      const int row = m0 + wm * 128 + mf * 16 + cr4;
#pragma unroll
      for (int j = 0; j < 4; j++)
        C[(size_t)(row + j) * N + col] = acc[mf][nf][j] * s;
    }
  }
#undef STAGE
#undef RD_A
#undef RD_B
#undef BAR
}

// ---- fallback: f32 tiled GEMM (odd shapes / tiny ws) ----
__global__ __launch_bounds__(256) void fallback_gemm_kernel(
    const float* __restrict__ x, const float* __restrict__ w,
    const float* __restrict__ scale, float* __restrict__ out,
    int M, int N, int K) {
  __shared__ float xs[16][17];
  __shared__ float ws_[16][17];
  int nb = N / 16;
  int bx = blockIdx.x % nb;
  int by = blockIdx.x / nb;
  int tx = threadIdx.x % 16;
  int ty = threadIdx.x / 16;
  float acc = 0.f;
  for (int k0 = 0; k0 < K; k0 += 16) {
    xs[ty][tx] = x[(size_t)(by * 16 + ty) * K + k0 + tx];
    float wv = w[(size_t)(bx * 16 + ty) * K + k0 + tx];
    ws_[ty][tx] = (float)((wv > 0.f) - (wv < 0.f));
    __syncthreads();
#pragma unroll
    for (int kk = 0; kk < 16; kk++) acc += xs[ty][kk] * ws_[tx][kk];
    __syncthreads();
  }
  int row = by * 16 + ty, col = bx * 16 + tx;
  out[(size_t)row * N + col] = acc * scale[col];
}

extern "C" void kernel_launch(void* const* d_in, const int* in_sizes, int n_in,
                              void* d_out, int out_size, void* d_ws, size_t ws_size,
                              hipStream_t stream) {
  const float* x = (const float*)d_in[0];
  const float* w = (const float*)d_in[1];
  const float* scale = (const float*)d_in[2];
  float* out = (float*)d_out;

  const int N = in_sizes[2];
  const int K = in_sizes[1] / N;
  const int M = in_sizes[0] / K;

  const size_t xb_bytes = (size_t)M * K * 2;
  const size_t wb_bytes = (size_t)N * K * 2;
  const bool shapes_ok = (M % 256 == 0) && (N % 256 == 0) && (K % 128 == 0);

  if (shapes_ok && ws_size >= xb_bytes + wb_bytes) {
    __hip_bfloat16* xb = (__hip_bfloat16*)d_ws;
    __hip_bfloat16* wb = (__hip_bfloat16*)((char*)d_ws + xb_bytes);

    cvt_x_kernel<<<2048, 256, 0, stream>>>((const float4*)x, (ushort4*)xb, M * (K / 4));
    binarize_w_kernel<<<2048, 256, 0, stream>>>((const float4*)w, (ushort4*)wb, N * (K / 4));

    int grid = (M / 256) * (N / 256);
    gemm256_kernel<<<grid, 512, 0, stream>>>(xb, wb, scale, out, M, N, K);
  } else {
    int grid = (M / 16) * (N / 16);
    fallback_gemm_kernel<<<grid, 256, 0, stream>>>(x, w, scale, out, M, N, K);
  }
}